// Round 6
// baseline (132.702 us; speedup 1.0000x reference)
//
#include <hip/hip_runtime.h>

// BatchWiseTripletLoss: n=8192 rows, d=128, scalar output.
// Round-6: barrier-free fragment-order GEMM passes (round 5) +
//  (a) 32 rows/wave -> ~120 unified regs -> 4 waves/SIMD (was 2),
//  (b) register ping-pong prefetch of next B stripe to hide L2 latency,
//  (c) pass1 fuses the partial-max combine in its prologue.
// ebB chunk (16B) at [(stripe*4+ks)*64+lane] holds row=stripe*16+(lane&15),
// elements [(ks*4+(lane>>4))*8 .. +8) — identical layout for A and B frags.

#define D 128
#define BM 128  // rows per block = 4 waves x 32
#define SPLIT 32
#define NPART SPLIT
#define MARGIN 0.1f
#define NEG_FLOOR 0.6f
#define NINF -1e30f

typedef short bf16x8 __attribute__((ext_vector_type(8)));
typedef float f32x4 __attribute__((ext_vector_type(4)));

__device__ __forceinline__ unsigned short f2bf(float f) {
  unsigned u = __float_as_uint(f);
  u += 0x7FFFu + ((u >> 16) & 1u);
  return (unsigned short)(u >> 16);
}

// ---- K1: L2-normalize rows, emit bf16 in fragment order ----
__global__ void k_normB(const float* __restrict__ emb,
                        uint4* __restrict__ ebB, int n) {
  const int s = blockIdx.x;         // 16-row stripe
  const int rl = threadIdx.x >> 4;  // row within stripe
  const int c = threadIdx.x & 15;   // 16B chunk within row
  const int row = s * 16 + rl;
  const float* p = emb + (size_t)row * D + c * 8;
  float4 v0 = *(const float4*)p;
  float4 v1 = *(const float4*)(p + 4);
  float ss = v0.x * v0.x + v0.y * v0.y + v0.z * v0.z + v0.w * v0.w +
             v1.x * v1.x + v1.y * v1.y + v1.z * v1.z + v1.w * v1.w;
#pragma unroll
  for (int off = 1; off < 16; off <<= 1) ss += __shfl_xor(ss, off, 64);
  float inv = 1.0f / fmaxf(sqrtf(ss), 1e-12f);
  uint4 wv;
  wv.x = (unsigned)f2bf(v0.x * inv) | ((unsigned)f2bf(v0.y * inv) << 16);
  wv.y = (unsigned)f2bf(v0.z * inv) | ((unsigned)f2bf(v0.w * inv) << 16);
  wv.z = (unsigned)f2bf(v1.x * inv) | ((unsigned)f2bf(v1.y * inv) << 16);
  wv.w = (unsigned)f2bf(v1.z * inv) | ((unsigned)f2bf(v1.w * inv) << 16);
  const int ks = c >> 2, g = c & 3;
  ebB[((s * 4 + ks) * 64) + (g * 16 + rl)] = wv;
}

// ---- K2/K4: barrier-free GEMM pass, 32 rows/wave, prefetched B ----
template <int PASS>
__global__ __launch_bounds__(256, 4) void k_pass3(
    const bf16x8* __restrict__ ebB, const int* __restrict__ tgt,
    float* __restrict__ mneg_p, float* __restrict__ mpos_p,
    float* __restrict__ loss_p, int n) {
  __shared__ float thrN[BM], thrP[BM];  // PASS1 only (1 KB)

  const int lane = threadIdx.x & 63;
  const int w = threadIdx.x >> 6;
  const int l15 = lane & 15, g = lane >> 4;

  const int m0 = blockIdx.x * BM;
  const int rbase = m0 + w * 32;  // this wave's 32-row panel
  const int sA = rbase >> 4;
  const int colsPer = n / SPLIT;  // 256
  const int cs0 = (blockIdx.y * colsPer) >> 4;
  const int pidx = blockIdx.y;

  // PASS1 prologue: combine NPART partial maxima -> per-row thresholds.
  if (PASS == 1) {
    int r0 = threadIdx.x & 127;
    bool which = threadIdx.x >= 128;
    const float* src = which ? mpos_p : mneg_p;
    float v = NINF;
#pragma unroll
    for (int s = 0; s < NPART; ++s) v = fmaxf(v, src[(size_t)s * n + m0 + r0]);
    if (which)
      thrP[r0] = fmaxf(NEG_FLOOR, v) - MARGIN;  // thr_neg
    else
      thrN[r0] = v + MARGIN;  // thr_pos
    __syncthreads();
  }

  // A fragments: 8 coalesced 1KB wave loads (32 regs).
  bf16x8 a[2][4];
#pragma unroll
  for (int mt = 0; mt < 2; ++mt)
#pragma unroll
    for (int ks = 0; ks < 4; ++ks)
      a[mt][ks] = ebB[((sA + mt) * 4 + ks) * 64 + lane];

  int tr[2][4];
#pragma unroll
  for (int mt = 0; mt < 2; ++mt) {
    int4 t4 = *(const int4*)(tgt + rbase + mt * 16 + g * 4);
    tr[mt][0] = t4.x; tr[mt][1] = t4.y; tr[mt][2] = t4.z; tr[mt][3] = t4.w;
  }

  float accN[2][4], accP[2][4], lossA[2][4];
#pragma unroll
  for (int mt = 0; mt < 2; ++mt)
#pragma unroll
    for (int r = 0; r < 4; ++r) {
      if (PASS == 0) {
        accN[mt][r] = NINF;
        accP[mt][r] = NINF;
      } else {
        int rl = w * 32 + mt * 16 + g * 4 + r;
        accN[mt][r] = thrN[rl];  // thr_pos
        accP[mt][r] = thrP[rl];  // thr_neg
        lossA[mt][r] = 0.0f;
      }
    }

  // One column-stripe step: compute with (bc,tcc), prefetch (bn,tcn).
  auto step = [&](bf16x8(&bc)[4], int tcc, bf16x8(&bn)[4], int& tcn, int si) {
    const int cs = cs0 + si;
    if (si < 15) {
      const int csn = cs + 1;
#pragma unroll
      for (int ks = 0; ks < 4; ++ks) bn[ks] = ebB[(csn * 4 + ks) * 64 + lane];
      tcn = tgt[csn * 16 + l15];
    }
    f32x4 acc[2];
#pragma unroll
    for (int mt = 0; mt < 2; ++mt) acc[mt] = (f32x4){0.f, 0.f, 0.f, 0.f};
#pragma unroll
    for (int ks = 0; ks < 4; ++ks)
#pragma unroll
      for (int mt = 0; mt < 2; ++mt)
        acc[mt] = __builtin_amdgcn_mfma_f32_16x16x32_bf16(a[mt][ks], bc[ks],
                                                          acc[mt], 0, 0, 0);
#pragma unroll
    for (int mt = 0; mt < 2; ++mt) {
      if (rbase + mt * 16 != cs * 16) {  // off-diagonal fast path
#pragma unroll
        for (int r = 0; r < 4; ++r) {
          float s = acc[mt][r];
          bool same = (tr[mt][r] == tcc);
          if (PASS == 0) {
            accN[mt][r] = fmaxf(accN[mt][r], same ? NINF : s);
            accP[mt][r] = fmaxf(accP[mt][r], same ? s : NINF);
          } else {
            float u = same ? 1.0f - s : s;
            bool c = same ? (s < accN[mt][r]) : (s > accP[mt][r]);
            lossA[mt][r] += c ? u : 0.f;
          }
        }
      } else {  // diagonal tile: exclude self-pair
#pragma unroll
        for (int r = 0; r < 4; ++r) {
          float s = acc[mt][r];
          bool same = (tr[mt][r] == tcc);
          bool posOk = same && ((g * 4 + r) != l15);
          if (PASS == 0) {
            accN[mt][r] = fmaxf(accN[mt][r], same ? NINF : s);
            accP[mt][r] = fmaxf(accP[mt][r], posOk ? s : NINF);
          } else {
            bool cpos = posOk && (s < accN[mt][r]);
            bool cneg = !same && (s > accP[mt][r]);
            lossA[mt][r] += cpos ? (1.0f - s) : (cneg ? s : 0.f);
          }
        }
      }
    }
  };

  bf16x8 b0[4], b1[4];
  int tc0 = tgt[cs0 * 16 + l15], tc1 = 0;
#pragma unroll
  for (int ks = 0; ks < 4; ++ks) b0[ks] = ebB[(cs0 * 4 + ks) * 64 + lane];
#pragma unroll
  for (int sp = 0; sp < 8; ++sp) {
    step(b0, tc0, b1, tc1, 2 * sp);
    step(b1, tc1, b0, tc0, 2 * sp + 1);
  }

  // Reduce over the 16 l15-lanes sharing each row; lane l15==0 writes.
#pragma unroll
  for (int mt = 0; mt < 2; ++mt) {
#pragma unroll
    for (int r = 0; r < 4; ++r) {
      int row = rbase + mt * 16 + g * 4 + r;
      if (PASS == 0) {
        float vn = accN[mt][r], vp = accP[mt][r];
#pragma unroll
        for (int off = 1; off < 16; off <<= 1) {
          vn = fmaxf(vn, __shfl_xor(vn, off, 64));
          vp = fmaxf(vp, __shfl_xor(vp, off, 64));
        }
        if (l15 == 0) {
          mneg_p[(size_t)pidx * n + row] = vn;
          mpos_p[(size_t)pidx * n + row] = vp;
        }
      } else {
        float vl = lossA[mt][r];
#pragma unroll
        for (int off = 1; off < 16; off <<= 1) vl += __shfl_xor(vl, off, 64);
        if (l15 == 0) loss_p[(size_t)pidx * n + row] = vl;
      }
    }
  }
}

// ---- K5a: per-chunk deterministic reduction (32 blocks x 256 rows) ----
__global__ void k_final1(const float* __restrict__ loss_p,
                         const float* __restrict__ mpos_p,
                         float* __restrict__ bpart, int n) {
  __shared__ float red[256];
  int i = blockIdx.x * 256 + threadIdx.x;
  float vp = NINF, acc = 0.f;
#pragma unroll
  for (int sp = 0; sp < NPART; ++sp) {
    vp = fmaxf(vp, mpos_p[(size_t)sp * n + i]);
    acc += loss_p[(size_t)sp * n + i];
  }
  acc = (vp > -1e29f) ? acc : 0.f;  // has_pos
  red[threadIdx.x] = acc;
  __syncthreads();
  for (int off = 128; off > 0; off >>= 1) {
    if ((int)threadIdx.x < off) red[threadIdx.x] += red[threadIdx.x + off];
    __syncthreads();
  }
  if (threadIdx.x == 0) bpart[blockIdx.x] = red[0];
}

// ---- K5b: final sum of block partials ----
__global__ void k_final2(const float* __restrict__ bpart,
                         float* __restrict__ out, int n, int nb) {
  int lane = threadIdx.x & 63;
  float v = (lane < nb) ? bpart[lane] : 0.f;
#pragma unroll
  for (int off = 1; off < 64; off <<= 1) v += __shfl_xor(v, off, 64);
  if (lane == 0) out[0] = v / (float)n;
}

extern "C" void kernel_launch(void* const* d_in, const int* in_sizes, int n_in,
                              void* d_out, int out_size, void* d_ws,
                              size_t ws_size, hipStream_t stream) {
  const float* emb = (const float*)d_in[0];
  const int* tgt = (const int*)d_in[1];
  float* out = (float*)d_out;
  const int n = in_sizes[1];  // 8192

  char* ws = (char*)d_ws;
  uint4* ebB = (uint4*)ws;  // fragment-ordered bf16 [n*D*2 bytes]
  size_t ebBytes = (size_t)n * D * sizeof(unsigned short);
  float* mneg_p = (float*)(ws + ebBytes);      // [NPART][n]
  float* mpos_p = mneg_p + (size_t)NPART * n;  // [NPART][n]
  float* loss_p = mpos_p + (size_t)NPART * n;  // [NPART][n]
  float* bpart = loss_p + (size_t)NPART * n;   // [32]

  k_normB<<<n / 16, 256, 0, stream>>>(emb, ebB, n);

  dim3 grid(n / BM, SPLIT);
  k_pass3<0><<<grid, 256, 0, stream>>>((const bf16x8*)ebB, tgt, mneg_p,
                                       mpos_p, loss_p, n);
  k_pass3<1><<<grid, 256, 0, stream>>>((const bf16x8*)ebB, tgt, mneg_p,
                                       mpos_p, loss_p, n);
  k_final1<<<n / 256, 256, 0, stream>>>(loss_p, mpos_p, bpart, n);
  k_final2<<<1, 64, 0, stream>>>(bpart, out, n, n / 256);
}

// Round 7
// 89.160 us; speedup vs baseline: 1.4884x; 1.4884x over previous
//
#include <hip/hip_runtime.h>

// BatchWiseTripletLoss: n=8192, d=128, 512 classes, scalar output.
// Round-7: counting-sort rows by class (deterministic), so same-class pairs
// are confined to tiles where the wave's (sorted) class range overlaps the
// column stripe's class range. Clean stripes run a 1-fmax/elem (pass0) or
// max-tree+vote (pass1) epilogue; dirty stripes run the full verified path.
// Keeps: fragment-order ebB (A/B share the per-lane k-permutation, safe for
// sim = E.E^T), 32 rows/wave, ping-pong B prefetch, launch_bounds(256,2)
// (the no-spill point; (256,4) spilled catastrophically in rounds 3 & 6).

#define D 128
#define BM 128  // rows per block = 4 waves x 32
#define SPLIT 32
#define NPART SPLIT
#define NCLS 512
#define MARGIN 0.1f
#define NEG_FLOOR 0.6f
#define NINF -1e30f

typedef short bf16x8 __attribute__((ext_vector_type(8)));
typedef float f32x4 __attribute__((ext_vector_type(4)));

__device__ __forceinline__ unsigned short f2bf(float f) {
  unsigned u = __float_as_uint(f);
  u += 0x7FFFu + ((u >> 16) & 1u);
  return (unsigned short)(u >> 16);
}

// ---- S1: per-chunk class histogram (64 chunks x 128 rows) ----
__global__ void k_hist(const int* __restrict__ tgt, int* __restrict__ H) {
  __shared__ int h[NCLS];
  for (int i = threadIdx.x; i < NCLS; i += 128) h[i] = 0;
  __syncthreads();
  atomicAdd(&h[tgt[blockIdx.x * 128 + threadIdx.x]], 1);
  __syncthreads();
  for (int i = threadIdx.x; i < NCLS; i += 128)
    H[blockIdx.x * NCLS + i] = h[i];
}

// ---- S2: one-block scan -> per-chunk per-class scatter bases ----
__global__ void k_scan(const int* __restrict__ H, int* __restrict__ CB) {
  __shared__ int wsum[8];
  const int c = threadIdx.x;  // class, 512 threads
  int t = 0;
#pragma unroll 8
  for (int k = 0; k < 64; ++k) t += H[k * NCLS + c];
  // exclusive scan of totals over 512 threads
  const int lane = c & 63, w = c >> 6;
  int v = t;
#pragma unroll
  for (int off = 1; off < 64; off <<= 1) {
    int u = __shfl_up(v, off, 64);
    if (lane >= off) v += u;
  }
  if (lane == 63) wsum[w] = v;
  __syncthreads();
  if (c < 8) {
    int x = wsum[c];
#pragma unroll
    for (int off = 1; off < 8; off <<= 1) {
      int u = __shfl_up(x, off, 64);
      if (lane >= off) x += u;
    }
    wsum[c] = x;  // inclusive wave sums
  }
  __syncthreads();
  int base = v + ((w > 0) ? wsum[w - 1] : 0) - t;  // exclusive prefix
  int run = base;
#pragma unroll 8
  for (int k = 0; k < 64; ++k) {
    CB[k * NCLS + c] = run;
    run += H[k * NCLS + c];
  }
}

// ---- S3: stable scatter (thread = class, block = chunk) ----
__global__ void k_scatter(const int* __restrict__ tgt,
                          const int* __restrict__ CB, int* __restrict__ perm) {
  const int c = threadIdx.x;  // 512 threads
  int pos = CB[blockIdx.x * NCLS + c];
  const int base = blockIdx.x * 128;
  for (int j = 0; j < 128; ++j) {
    int cls = tgt[base + j];
    if (cls == c) perm[pos++] = base + j;
  }
}

// ---- K1: gather-normalize rows into fragment-order bf16 ----
// ebB chunk (16B) at [(stripe*4+ks)*64+lane] holds sorted row
// stripe*16+(lane&15), elements [(ks*4+(lane>>4))*8 .. +8).
__global__ void k_normB(const float* __restrict__ emb,
                        const int* __restrict__ tgt,
                        const int* __restrict__ perm, uint4* __restrict__ ebB,
                        int* __restrict__ tgtS, int n) {
  const int s = blockIdx.x;         // 16-row (sorted) stripe
  const int rl = threadIdx.x >> 4;  // row within stripe
  const int c = threadIdx.x & 15;   // 16B chunk within row
  const int p = s * 16 + rl;        // sorted row
  const int orig = perm[p];
  const float* q = emb + (size_t)orig * D + c * 8;
  float4 v0 = *(const float4*)q;
  float4 v1 = *(const float4*)(q + 4);
  float ss = v0.x * v0.x + v0.y * v0.y + v0.z * v0.z + v0.w * v0.w +
             v1.x * v1.x + v1.y * v1.y + v1.z * v1.z + v1.w * v1.w;
#pragma unroll
  for (int off = 1; off < 16; off <<= 1) ss += __shfl_xor(ss, off, 64);
  float inv = 1.0f / fmaxf(sqrtf(ss), 1e-12f);
  uint4 wv;
  wv.x = (unsigned)f2bf(v0.x * inv) | ((unsigned)f2bf(v0.y * inv) << 16);
  wv.y = (unsigned)f2bf(v0.z * inv) | ((unsigned)f2bf(v0.w * inv) << 16);
  wv.z = (unsigned)f2bf(v1.x * inv) | ((unsigned)f2bf(v1.y * inv) << 16);
  wv.w = (unsigned)f2bf(v1.z * inv) | ((unsigned)f2bf(v1.w * inv) << 16);
  const int ks = c >> 2, g = c & 3;
  ebB[((s * 4 + ks) * 64) + (g * 16 + rl)] = wv;
  if (c == 0) tgtS[p] = tgt[orig];
}

// ---- K2/K4: barrier-free GEMM pass, sorted-class fast/dirty epilogue ----
template <int PASS>
__global__ __launch_bounds__(256, 2) void k_pass4(
    const bf16x8* __restrict__ ebB, const int* __restrict__ tgtS,
    float* __restrict__ mneg_p, float* __restrict__ mpos_p,
    const float* __restrict__ thrNv, const float* __restrict__ thrPv,
    float* __restrict__ loss_p, int n) {
  const int lane = threadIdx.x & 63;
  const int w = threadIdx.x >> 6;
  const int l15 = lane & 15, g = lane >> 4;

  const int m0 = blockIdx.x * BM;
  const int rbase = m0 + w * 32;  // this wave's 32-row panel (sorted coords)
  const int sA = rbase >> 4;
  const int colsPer = n / SPLIT;            // 256
  const int cs0 = (blockIdx.y * colsPer) >> 4;  // first of 16 col stripes
  const int pidx = blockIdx.y;

  // Wave's class range (classes sorted -> endpoints suffice).
  const int clo = tgtS[rbase], chi = tgtS[rbase + 31];

  // A fragments: 8 coalesced 1KB wave loads (32 regs).
  bf16x8 a[2][4];
#pragma unroll
  for (int mt = 0; mt < 2; ++mt)
#pragma unroll
    for (int ks = 0; ks < 4; ++ks)
      a[mt][ks] = ebB[((sA + mt) * 4 + ks) * 64 + lane];

  int tr[2][4];  // row classes (dirty path only, but cheap to hold)
#pragma unroll
  for (int mt = 0; mt < 2; ++mt) {
    int4 t4 = *(const int4*)(tgtS + rbase + mt * 16 + g * 4);
    tr[mt][0] = t4.x; tr[mt][1] = t4.y; tr[mt][2] = t4.z; tr[mt][3] = t4.w;
  }

  // PASS0: accN/accP are running maxima. PASS1: they hold thrN/thrP.
  float accN[2][4], accP[2][4], lossA[2][4];
  float thrPmin = 0.f;
#pragma unroll
  for (int mt = 0; mt < 2; ++mt) {
    if (PASS == 0) {
#pragma unroll
      for (int r = 0; r < 4; ++r) {
        accN[mt][r] = NINF;
        accP[mt][r] = NINF;
      }
    } else {
      f32x4 vN = *(const f32x4*)(thrNv + rbase + mt * 16 + g * 4);
      f32x4 vP = *(const f32x4*)(thrPv + rbase + mt * 16 + g * 4);
#pragma unroll
      for (int r = 0; r < 4; ++r) {
        accN[mt][r] = vN[r];
        accP[mt][r] = vP[r];
        lossA[mt][r] = 0.0f;
      }
    }
  }
  if (PASS == 1) {  // wave-min of thrP (>= 0.5 thanks to the 0.6 floor)
    float m = accP[0][0];
#pragma unroll
    for (int mt = 0; mt < 2; ++mt)
#pragma unroll
      for (int r = 0; r < 4; ++r) m = fminf(m, accP[mt][r]);
#pragma unroll
    for (int off = 1; off < 64; off <<= 1) m = fminf(m, __shfl_xor(m, off, 64));
    thrPmin = m;
  }

  auto step = [&](bf16x8(&bc)[4], bf16x8(&bn)[4], int si) {
    const int cs = cs0 + si;
    if (si < 15) {
#pragma unroll
      for (int ks = 0; ks < 4; ++ks)
        bn[ks] = ebB[((cs + 1) * 4 + ks) * 64 + lane];
    }
    // Stripe class range (scalar loads; overlap test is wave-uniform).
    const int slo = tgtS[cs * 16], shi = tgtS[cs * 16 + 15];
    const bool dirty = (clo <= shi) && (slo <= chi);

    f32x4 acc[2];
#pragma unroll
    for (int mt = 0; mt < 2; ++mt) acc[mt] = (f32x4){0.f, 0.f, 0.f, 0.f};
#pragma unroll
    for (int ks = 0; ks < 4; ++ks)
#pragma unroll
      for (int mt = 0; mt < 2; ++mt)
        acc[mt] = __builtin_amdgcn_mfma_f32_16x16x32_bf16(a[mt][ks], bc[ks],
                                                          acc[mt], 0, 0, 0);
    if (!dirty) {  // pure negatives (no same-class pair anywhere in stripe)
      if (PASS == 0) {
#pragma unroll
        for (int mt = 0; mt < 2; ++mt)
#pragma unroll
          for (int r = 0; r < 4; ++r)
            accN[mt][r] = fmaxf(accN[mt][r], acc[mt][r]);
      } else {
#pragma unroll
        for (int mt = 0; mt < 2; ++mt) {
          float mx = fmaxf(fmaxf(acc[mt][0], acc[mt][1]),
                           fmaxf(acc[mt][2], acc[mt][3]));
          if (__any(mx > thrPmin)) {  // rare: some neg beats a threshold
#pragma unroll
            for (int r = 0; r < 4; ++r) {
              float s = acc[mt][r];
              lossA[mt][r] += (s > accP[mt][r]) ? s : 0.f;
            }
          }
        }
      }
    } else {  // overlap: full verified path (includes diagonal handling)
      const int tc = tgtS[cs * 16 + l15];
#pragma unroll
      for (int mt = 0; mt < 2; ++mt) {
        const bool diagT = (rbase + mt * 16 == cs * 16);
#pragma unroll
        for (int r = 0; r < 4; ++r) {
          float s = acc[mt][r];
          bool same = (tr[mt][r] == tc);
          bool posOk = same && !(diagT && ((g * 4 + r) == l15));
          if (PASS == 0) {
            accN[mt][r] = fmaxf(accN[mt][r], same ? NINF : s);
            accP[mt][r] = fmaxf(accP[mt][r], posOk ? s : NINF);
          } else {
            bool cpos = posOk && (s < accN[mt][r]);
            bool cneg = !same && (s > accP[mt][r]);
            lossA[mt][r] += cpos ? (1.0f - s) : (cneg ? s : 0.f);
          }
        }
      }
    }
  };

  bf16x8 b0[4], b1[4];
#pragma unroll
  for (int ks = 0; ks < 4; ++ks) b0[ks] = ebB[(cs0 * 4 + ks) * 64 + lane];
#pragma unroll
  for (int sp = 0; sp < 8; ++sp) {
    step(b0, b1, 2 * sp);
    step(b1, b0, 2 * sp + 1);
  }

  // Reduce over the 16 l15-lanes sharing each row; lane l15==0 writes.
#pragma unroll
  for (int mt = 0; mt < 2; ++mt) {
#pragma unroll
    for (int r = 0; r < 4; ++r) {
      int row = rbase + mt * 16 + g * 4 + r;
      if (PASS == 0) {
        float vn = accN[mt][r], vp = accP[mt][r];
#pragma unroll
        for (int off = 1; off < 16; off <<= 1) {
          vn = fmaxf(vn, __shfl_xor(vn, off, 64));
          vp = fmaxf(vp, __shfl_xor(vp, off, 64));
        }
        if (l15 == 0) {
          mneg_p[(size_t)pidx * n + row] = vn;
          mpos_p[(size_t)pidx * n + row] = vp;
        }
      } else {
        float vl = lossA[mt][r];
#pragma unroll
        for (int off = 1; off < 16; off <<= 1) vl += __shfl_xor(vl, off, 64);
        if (l15 == 0) loss_p[(size_t)pidx * n + row] = vl;
      }
    }
  }
}

// ---- K3: combine partial maxima -> per-row thresholds + has_pos ----
__global__ void k_combine(const float* __restrict__ mneg_p,
                          const float* __restrict__ mpos_p,
                          float* __restrict__ thrNv, float* __restrict__ thrPv,
                          float* __restrict__ hasp, int n) {
  int i = blockIdx.x * blockDim.x + threadIdx.x;
  if (i >= n) return;
  float vn = NINF, vp = NINF;
#pragma unroll
  for (int s = 0; s < NPART; ++s) {
    vn = fmaxf(vn, mneg_p[(size_t)s * n + i]);
    vp = fmaxf(vp, mpos_p[(size_t)s * n + i]);
  }
  thrNv[i] = vn + MARGIN;                     // thr_pos
  thrPv[i] = fmaxf(NEG_FLOOR, vp) - MARGIN;   // thr_neg (>= 0.5)
  hasp[i] = (vp > -1e29f) ? 1.f : 0.f;
}

// ---- K5a/K5b: deterministic final reduction ----
__global__ void k_final1(const float* __restrict__ loss_p,
                         const float* __restrict__ hasp,
                         float* __restrict__ bpart, int n) {
  __shared__ float red[256];
  int i = blockIdx.x * 256 + threadIdx.x;
  float acc = 0.f;
#pragma unroll
  for (int sp = 0; sp < NPART; ++sp) acc += loss_p[(size_t)sp * n + i];
  acc *= hasp[i];
  red[threadIdx.x] = acc;
  __syncthreads();
  for (int off = 128; off > 0; off >>= 1) {
    if ((int)threadIdx.x < off) red[threadIdx.x] += red[threadIdx.x + off];
    __syncthreads();
  }
  if (threadIdx.x == 0) bpart[blockIdx.x] = red[0];
}

__global__ void k_final2(const float* __restrict__ bpart,
                         float* __restrict__ out, int n, int nb) {
  int lane = threadIdx.x & 63;
  float v = (lane < nb) ? bpart[lane] : 0.f;
#pragma unroll
  for (int off = 1; off < 64; off <<= 1) v += __shfl_xor(v, off, 64);
  if (lane == 0) out[0] = v / (float)n;
}

extern "C" void kernel_launch(void* const* d_in, const int* in_sizes, int n_in,
                              void* d_out, int out_size, void* d_ws,
                              size_t ws_size, hipStream_t stream) {
  const float* emb = (const float*)d_in[0];
  const int* tgt = (const int*)d_in[1];
  float* out = (float*)d_out;
  const int n = in_sizes[1];  // 8192

  char* ws = (char*)d_ws;
  uint4* ebB = (uint4*)ws;  // fragment-ordered bf16, 2 MB
  size_t off = (size_t)n * D * sizeof(unsigned short);
  float* mneg_p = (float*)(ws + off);          // [NPART][n]
  float* mpos_p = mneg_p + (size_t)NPART * n;  // [NPART][n]
  float* loss_p = mpos_p + (size_t)NPART * n;  // [NPART][n]
  float* thrNv = loss_p + (size_t)NPART * n;   // [n]
  float* thrPv = thrNv + n;                    // [n]
  float* hasp = thrPv + n;                     // [n]
  float* bpart = hasp + n;                     // [32]
  int* H = (int*)(bpart + 64);                 // [64][512]
  int* CB = H + 64 * NCLS;                     // [64][512]
  int* perm = CB + 64 * NCLS;                  // [n]
  int* tgtS = perm + n;                        // [n]

  k_hist<<<n / 128, 128, 0, stream>>>(tgt, H);
  k_scan<<<1, NCLS, 0, stream>>>(H, CB);
  k_scatter<<<n / 128, NCLS, 0, stream>>>(tgt, CB, perm);
  k_normB<<<n / 16, 256, 0, stream>>>(emb, tgt, perm, ebB, tgtS, n);

  dim3 grid(n / BM, SPLIT);
  k_pass4<0><<<grid, 256, 0, stream>>>((const bf16x8*)ebB, tgtS, mneg_p,
                                       mpos_p, thrNv, thrPv, loss_p, n);
  k_combine<<<(n + 255) / 256, 256, 0, stream>>>(mneg_p, mpos_p, thrNv, thrPv,
                                                 hasp, n);
  k_pass4<1><<<grid, 256, 0, stream>>>((const bf16x8*)ebB, tgtS, mneg_p,
                                       mpos_p, thrNv, thrPv, loss_p, n);
  k_final1<<<n / 256, 256, 0, stream>>>(loss_p, hasp, bpart, n);
  k_final2<<<1, 64, 0, stream>>>(bpart, out, n, n / 256);
}

// Round 8
// 89.022 us; speedup vs baseline: 1.4907x; 1.0016x over previous
//
#include <hip/hip_runtime.h>

// BatchWiseTripletLoss: n=8192, d=128, 512 classes, scalar output.
// Round-7: counting-sort rows by class (deterministic), so same-class pairs
// are confined to tiles where the wave's (sorted) class range overlaps the
// column stripe's class range. Clean stripes run a 1-fmax/elem (pass0) or
// max-tree+vote (pass1) epilogue; dirty stripes run the full verified path.
// Keeps: fragment-order ebB (A/B share the per-lane k-permutation, safe for
// sim = E.E^T), 32 rows/wave, ping-pong B prefetch, launch_bounds(256,2)
// (the no-spill point; (256,4) spilled catastrophically in rounds 3 & 6).

#define D 128
#define BM 128  // rows per block = 4 waves x 32
#define SPLIT 32
#define NPART SPLIT
#define NCLS 512
#define MARGIN 0.1f
#define NEG_FLOOR 0.6f
#define NINF -1e30f

typedef short bf16x8 __attribute__((ext_vector_type(8)));
typedef float f32x4 __attribute__((ext_vector_type(4)));

__device__ __forceinline__ unsigned short f2bf(float f) {
  unsigned u = __float_as_uint(f);
  u += 0x7FFFu + ((u >> 16) & 1u);
  return (unsigned short)(u >> 16);
}

// ---- S1: per-chunk class histogram (64 chunks x 128 rows) ----
__global__ void k_hist(const int* __restrict__ tgt, int* __restrict__ H) {
  __shared__ int h[NCLS];
  for (int i = threadIdx.x; i < NCLS; i += 128) h[i] = 0;
  __syncthreads();
  atomicAdd(&h[tgt[blockIdx.x * 128 + threadIdx.x]], 1);
  __syncthreads();
  for (int i = threadIdx.x; i < NCLS; i += 128)
    H[blockIdx.x * NCLS + i] = h[i];
}

// ---- S2: one-block scan -> per-chunk per-class scatter bases ----
__global__ void k_scan(const int* __restrict__ H, int* __restrict__ CB) {
  __shared__ int wsum[8];
  const int c = threadIdx.x;  // class, 512 threads
  int t = 0;
#pragma unroll 8
  for (int k = 0; k < 64; ++k) t += H[k * NCLS + c];
  // exclusive scan of totals over 512 threads
  const int lane = c & 63, w = c >> 6;
  int v = t;
#pragma unroll
  for (int off = 1; off < 64; off <<= 1) {
    int u = __shfl_up(v, off, 64);
    if (lane >= off) v += u;
  }
  if (lane == 63) wsum[w] = v;
  __syncthreads();
  if (c < 8) {
    int x = wsum[c];
#pragma unroll
    for (int off = 1; off < 8; off <<= 1) {
      int u = __shfl_up(x, off, 64);
      if (lane >= off) x += u;
    }
    wsum[c] = x;  // inclusive wave sums
  }
  __syncthreads();
  int base = v + ((w > 0) ? wsum[w - 1] : 0) - t;  // exclusive prefix
  int run = base;
#pragma unroll 8
  for (int k = 0; k < 64; ++k) {
    CB[k * NCLS + c] = run;
    run += H[k * NCLS + c];
  }
}

// ---- S3: stable scatter (thread = class, block = chunk) ----
__global__ void k_scatter(const int* __restrict__ tgt,
                          const int* __restrict__ CB, int* __restrict__ perm) {
  const int c = threadIdx.x;  // 512 threads
  int pos = CB[blockIdx.x * NCLS + c];
  const int base = blockIdx.x * 128;
  for (int j = 0; j < 128; ++j) {
    int cls = tgt[base + j];
    if (cls == c) perm[pos++] = base + j;
  }
}

// ---- K1: gather-normalize rows into fragment-order bf16 ----
// ebB chunk (16B) at [(stripe*4+ks)*64+lane] holds sorted row
// stripe*16+(lane&15), elements [(ks*4+(lane>>4))*8 .. +8).
__global__ void k_normB(const float* __restrict__ emb,
                        const int* __restrict__ tgt,
                        const int* __restrict__ perm, uint4* __restrict__ ebB,
                        int* __restrict__ tgtS, int n) {
  const int s = blockIdx.x;         // 16-row (sorted) stripe
  const int rl = threadIdx.x >> 4;  // row within stripe
  const int c = threadIdx.x & 15;   // 16B chunk within row
  const int p = s * 16 + rl;        // sorted row
  const int orig = perm[p];
  const float* q = emb + (size_t)orig * D + c * 8;
  float4 v0 = *(const float4*)q;
  float4 v1 = *(const float4*)(q + 4);
  float ss = v0.x * v0.x + v0.y * v0.y + v0.z * v0.z + v0.w * v0.w +
             v1.x * v1.x + v1.y * v1.y + v1.z * v1.z + v1.w * v1.w;
#pragma unroll
  for (int off = 1; off < 16; off <<= 1) ss += __shfl_xor(ss, off, 64);
  float inv = 1.0f / fmaxf(sqrtf(ss), 1e-12f);
  uint4 wv;
  wv.x = (unsigned)f2bf(v0.x * inv) | ((unsigned)f2bf(v0.y * inv) << 16);
  wv.y = (unsigned)f2bf(v0.z * inv) | ((unsigned)f2bf(v0.w * inv) << 16);
  wv.z = (unsigned)f2bf(v1.x * inv) | ((unsigned)f2bf(v1.y * inv) << 16);
  wv.w = (unsigned)f2bf(v1.z * inv) | ((unsigned)f2bf(v1.w * inv) << 16);
  const int ks = c >> 2, g = c & 3;
  ebB[((s * 4 + ks) * 64) + (g * 16 + rl)] = wv;
  if (c == 0) tgtS[p] = tgt[orig];
}

// ---- K2/K4: barrier-free GEMM pass, sorted-class fast/dirty epilogue ----
template <int PASS>
__global__ __launch_bounds__(256, 2) void k_pass4(
    const bf16x8* __restrict__ ebB, const int* __restrict__ tgtS,
    float* __restrict__ mneg_p, float* __restrict__ mpos_p,
    const float* __restrict__ thrNv, const float* __restrict__ thrPv,
    float* __restrict__ loss_p, int n) {
  const int lane = threadIdx.x & 63;
  const int w = threadIdx.x >> 6;
  const int l15 = lane & 15, g = lane >> 4;

  const int m0 = blockIdx.x * BM;
  const int rbase = m0 + w * 32;  // this wave's 32-row panel (sorted coords)
  const int sA = rbase >> 4;
  const int colsPer = n / SPLIT;            // 256
  const int cs0 = (blockIdx.y * colsPer) >> 4;  // first of 16 col stripes
  const int pidx = blockIdx.y;

  // Wave's class range (classes sorted -> endpoints suffice).
  const int clo = tgtS[rbase], chi = tgtS[rbase + 31];

  // A fragments: 8 coalesced 1KB wave loads (32 regs).
  bf16x8 a[2][4];
#pragma unroll
  for (int mt = 0; mt < 2; ++mt)
#pragma unroll
    for (int ks = 0; ks < 4; ++ks)
      a[mt][ks] = ebB[((sA + mt) * 4 + ks) * 64 + lane];

  int tr[2][4];  // row classes (dirty path only, but cheap to hold)
#pragma unroll
  for (int mt = 0; mt < 2; ++mt) {
    int4 t4 = *(const int4*)(tgtS + rbase + mt * 16 + g * 4);
    tr[mt][0] = t4.x; tr[mt][1] = t4.y; tr[mt][2] = t4.z; tr[mt][3] = t4.w;
  }

  // PASS0: accN/accP are running maxima. PASS1: they hold thrN/thrP.
  float accN[2][4], accP[2][4], lossA[2][4];
  float thrPmin = 0.f;
#pragma unroll
  for (int mt = 0; mt < 2; ++mt) {
    if (PASS == 0) {
#pragma unroll
      for (int r = 0; r < 4; ++r) {
        accN[mt][r] = NINF;
        accP[mt][r] = NINF;
      }
    } else {
      f32x4 vN = *(const f32x4*)(thrNv + rbase + mt * 16 + g * 4);
      f32x4 vP = *(const f32x4*)(thrPv + rbase + mt * 16 + g * 4);
#pragma unroll
      for (int r = 0; r < 4; ++r) {
        accN[mt][r] = vN[r];
        accP[mt][r] = vP[r];
        lossA[mt][r] = 0.0f;
      }
    }
  }
  if (PASS == 1) {  // wave-min of thrP (>= 0.5 thanks to the 0.6 floor)
    float m = accP[0][0];
#pragma unroll
    for (int mt = 0; mt < 2; ++mt)
#pragma unroll
      for (int r = 0; r < 4; ++r) m = fminf(m, accP[mt][r]);
#pragma unroll
    for (int off = 1; off < 64; off <<= 1) m = fminf(m, __shfl_xor(m, off, 64));
    thrPmin = m;
  }

  auto step = [&](bf16x8(&bc)[4], bf16x8(&bn)[4], int si) {
    const int cs = cs0 + si;
    if (si < 15) {
#pragma unroll
      for (int ks = 0; ks < 4; ++ks)
        bn[ks] = ebB[((cs + 1) * 4 + ks) * 64 + lane];
    }
    // Stripe class range (scalar loads; overlap test is wave-uniform).
    const int slo = tgtS[cs * 16], shi = tgtS[cs * 16 + 15];
    const bool dirty = (clo <= shi) && (slo <= chi);

    f32x4 acc[2];
#pragma unroll
    for (int mt = 0; mt < 2; ++mt) acc[mt] = (f32x4){0.f, 0.f, 0.f, 0.f};
#pragma unroll
    for (int ks = 0; ks < 4; ++ks)
#pragma unroll
      for (int mt = 0; mt < 2; ++mt)
        acc[mt] = __builtin_amdgcn_mfma_f32_16x16x32_bf16(a[mt][ks], bc[ks],
                                                          acc[mt], 0, 0, 0);
    if (!dirty) {  // pure negatives (no same-class pair anywhere in stripe)
      if (PASS == 0) {
#pragma unroll
        for (int mt = 0; mt < 2; ++mt)
#pragma unroll
          for (int r = 0; r < 4; ++r)
            accN[mt][r] = fmaxf(accN[mt][r], acc[mt][r]);
      } else {
#pragma unroll
        for (int mt = 0; mt < 2; ++mt) {
          float mx = fmaxf(fmaxf(acc[mt][0], acc[mt][1]),
                           fmaxf(acc[mt][2], acc[mt][3]));
          if (__any(mx > thrPmin)) {  // rare: some neg beats a threshold
#pragma unroll
            for (int r = 0; r < 4; ++r) {
              float s = acc[mt][r];
              lossA[mt][r] += (s > accP[mt][r]) ? s : 0.f;
            }
          }
        }
      }
    } else {  // overlap: full verified path (includes diagonal handling)
      const int tc = tgtS[cs * 16 + l15];
#pragma unroll
      for (int mt = 0; mt < 2; ++mt) {
        const bool diagT = (rbase + mt * 16 == cs * 16);
#pragma unroll
        for (int r = 0; r < 4; ++r) {
          float s = acc[mt][r];
          bool same = (tr[mt][r] == tc);
          bool posOk = same && !(diagT && ((g * 4 + r) == l15));
          if (PASS == 0) {
            accN[mt][r] = fmaxf(accN[mt][r], same ? NINF : s);
            accP[mt][r] = fmaxf(accP[mt][r], posOk ? s : NINF);
          } else {
            bool cpos = posOk && (s < accN[mt][r]);
            bool cneg = !same && (s > accP[mt][r]);
            lossA[mt][r] += cpos ? (1.0f - s) : (cneg ? s : 0.f);
          }
        }
      }
    }
  };

  bf16x8 b0[4], b1[4];
#pragma unroll
  for (int ks = 0; ks < 4; ++ks) b0[ks] = ebB[(cs0 * 4 + ks) * 64 + lane];
#pragma unroll
  for (int sp = 0; sp < 8; ++sp) {
    step(b0, b1, 2 * sp);
    step(b1, b0, 2 * sp + 1);
  }

  // Reduce over the 16 l15-lanes sharing each row; lane l15==0 writes.
#pragma unroll
  for (int mt = 0; mt < 2; ++mt) {
#pragma unroll
    for (int r = 0; r < 4; ++r) {
      int row = rbase + mt * 16 + g * 4 + r;
      if (PASS == 0) {
        float vn = accN[mt][r], vp = accP[mt][r];
#pragma unroll
        for (int off = 1; off < 16; off <<= 1) {
          vn = fmaxf(vn, __shfl_xor(vn, off, 64));
          vp = fmaxf(vp, __shfl_xor(vp, off, 64));
        }
        if (l15 == 0) {
          mneg_p[(size_t)pidx * n + row] = vn;
          mpos_p[(size_t)pidx * n + row] = vp;
        }
      } else {
        float vl = lossA[mt][r];
#pragma unroll
        for (int off = 1; off < 16; off <<= 1) vl += __shfl_xor(vl, off, 64);
        if (l15 == 0) loss_p[(size_t)pidx * n + row] = vl;
      }
    }
  }
}

// ---- K3: combine partial maxima -> per-row thresholds + has_pos ----
__global__ void k_combine(const float* __restrict__ mneg_p,
                          const float* __restrict__ mpos_p,
                          float* __restrict__ thrNv, float* __restrict__ thrPv,
                          float* __restrict__ hasp, int n) {
  int i = blockIdx.x * blockDim.x + threadIdx.x;
  if (i >= n) return;
  float vn = NINF, vp = NINF;
#pragma unroll
  for (int s = 0; s < NPART; ++s) {
    vn = fmaxf(vn, mneg_p[(size_t)s * n + i]);
    vp = fmaxf(vp, mpos_p[(size_t)s * n + i]);
  }
  thrNv[i] = vn + MARGIN;                     // thr_pos
  thrPv[i] = fmaxf(NEG_FLOOR, vp) - MARGIN;   // thr_neg (>= 0.5)
  hasp[i] = (vp > -1e29f) ? 1.f : 0.f;
}

// ---- K5a/K5b: deterministic final reduction ----
__global__ void k_final1(const float* __restrict__ loss_p,
                         const float* __restrict__ hasp,
                         float* __restrict__ bpart, int n) {
  __shared__ float red[256];
  int i = blockIdx.x * 256 + threadIdx.x;
  float acc = 0.f;
#pragma unroll
  for (int sp = 0; sp < NPART; ++sp) acc += loss_p[(size_t)sp * n + i];
  acc *= hasp[i];
  red[threadIdx.x] = acc;
  __syncthreads();
  for (int off = 128; off > 0; off >>= 1) {
    if ((int)threadIdx.x < off) red[threadIdx.x] += red[threadIdx.x + off];
    __syncthreads();
  }
  if (threadIdx.x == 0) bpart[blockIdx.x] = red[0];
}

__global__ void k_final2(const float* __restrict__ bpart,
                         float* __restrict__ out, int n, int nb) {
  int lane = threadIdx.x & 63;
  float v = (lane < nb) ? bpart[lane] : 0.f;
#pragma unroll
  for (int off = 1; off < 64; off <<= 1) v += __shfl_xor(v, off, 64);
  if (lane == 0) out[0] = v / (float)n;
}

extern "C" void kernel_launch(void* const* d_in, const int* in_sizes, int n_in,
                              void* d_out, int out_size, void* d_ws,
                              size_t ws_size, hipStream_t stream) {
  const float* emb = (const float*)d_in[0];
  const int* tgt = (const int*)d_in[1];
  float* out = (float*)d_out;
  const int n = in_sizes[1];  // 8192

  char* ws = (char*)d_ws;
  uint4* ebB = (uint4*)ws;  // fragment-ordered bf16, 2 MB
  size_t off = (size_t)n * D * sizeof(unsigned short);
  float* mneg_p = (float*)(ws + off);          // [NPART][n]
  float* mpos_p = mneg_p + (size_t)NPART * n;  // [NPART][n]
  float* loss_p = mpos_p + (size_t)NPART * n;  // [NPART][n]
  float* thrNv = loss_p + (size_t)NPART * n;   // [n]
  float* thrPv = thrNv + n;                    // [n]
  float* hasp = thrPv + n;                     // [n]
  float* bpart = hasp + n;                     // [32]
  int* H = (int*)(bpart + 64);                 // [64][512]
  int* CB = H + 64 * NCLS;                     // [64][512]
  int* perm = CB + 64 * NCLS;                  // [n]
  int* tgtS = perm + n;                        // [n]

  k_hist<<<n / 128, 128, 0, stream>>>(tgt, H);
  k_scan<<<1, NCLS, 0, stream>>>(H, CB);
  k_scatter<<<n / 128, NCLS, 0, stream>>>(tgt, CB, perm);
  k_normB<<<n / 16, 256, 0, stream>>>(emb, tgt, perm, ebB, tgtS, n);

  dim3 grid(n / BM, SPLIT);
  k_pass4<0><<<grid, 256, 0, stream>>>((const bf16x8*)ebB, tgtS, mneg_p,
                                       mpos_p, thrNv, thrPv, loss_p, n);
  k_combine<<<(n + 255) / 256, 256, 0, stream>>>(mneg_p, mpos_p, thrNv, thrPv,
                                                 hasp, n);
  k_pass4<1><<<grid, 256, 0, stream>>>((const bf16x8*)ebB, tgtS, mneg_p,
                                       mpos_p, thrNv, thrPv, loss_p, n);
  k_final1<<<n / 256, 256, 0, stream>>>(loss_p, hasp, bpart, n);
  k_final2<<<1, 64, 0, stream>>>(bpart, out, n, n / 256);
}